// Round 1
// baseline (111.916 us; speedup 1.0000x reference)
//
#include <hip/hip_runtime.h>
#include <math.h>

#define N_EV   1024
#define M_PAST 2048
#define T_GRID 64
#define G_GRID 512
#define D_COV  16
#define EPS_F  1e-6f

// ---------------------------------------------------------------------------
// Kernel 0: zero the integral accumulator slot (d_out is poisoned 0xAA).
// ---------------------------------------------------------------------------
__global__ void zero_kernel(float* __restrict__ out) {
    out[N_EV] = 0.0f;
}

// ---------------------------------------------------------------------------
// Kernel 1: base intensity sum over the (T*G, D) grid:
//   sum_k max(z_flat[k] . beta, EPS) * dxdy * dt_step  -> atomicAdd(out[N])
// 128 blocks x 256 threads; one row per thread (32768 rows exactly).
// ---------------------------------------------------------------------------
__global__ __launch_bounds__(256) void base_kernel(
    const float* __restrict__ z_grid,   // (T*G, D) row-major
    const float* __restrict__ beta,     // (D,)
    const float* __restrict__ t_grid,   // (T,)
    float* __restrict__ out) {
    const int tid = threadIdx.x;
    const int row = blockIdx.x * 256 + tid;   // 0..32767

    const float4* b4 = (const float4*)beta;
    float4 b0 = b4[0], b1 = b4[1], b2 = b4[2], b3 = b4[3];

    const float4* z4 = (const float4*)(z_grid + (size_t)row * D_COV);
    float4 z0 = z4[0], z1 = z4[1], z2 = z4[2], z3 = z4[3];

    float dot = z0.x*b0.x + z0.y*b0.y + z0.z*b0.z + z0.w*b0.w
              + z1.x*b1.x + z1.y*b1.y + z1.z*b1.z + z1.w*b1.w
              + z2.x*b2.x + z2.y*b2.y + z2.z*b2.z + z2.w*b2.w
              + z3.x*b3.x + z3.y*b3.y + z3.z*b3.z + z3.w*b3.w;
    float v = fmaxf(dot, EPS_F);

    // block reduction: wave64 shuffle + LDS across 4 waves
    for (int o = 32; o > 0; o >>= 1) v += __shfl_down(v, o, 64);
    __shared__ float sw[4];
    const int lane = tid & 63, wave = tid >> 6;
    if (lane == 0) sw[wave] = v;
    __syncthreads();
    if (tid == 0) {
        float s = sw[0] + sw[1] + sw[2] + sw[3];
        float dt_step = t_grid[1] - t_grid[0];
        float scale = (1.0f / (float)G_GRID) * dt_step;
        atomicAdd(out + N_EV, s * scale);
    }
}

// ---------------------------------------------------------------------------
// Kernel 2: per-event kernel. One block (256 threads) per event i.
//   - exc_i   = sum_j  [t_i > past_t_ij] exp(-|x_i-past_x_ij|^2/(2s^2) - w*dt)
//   - Sg_i    = sum_g  exp(-|x_grid_g - x_i|^2/(2s^2))        (no mask)
//   - Tt_i    = sum_ti [t_grid_ti > t_i] exp(-w*(t_grid_ti - t_i))
//   out[i]    = log(max(cov_i.beta, EPS) + c*exc_i + EPS),  c = a*w/(2*pi*s^2)
//   atomicAdd(out[N], c * Sg_i * Tt_i * dxdy * dt_step)      (separable sum)
// ---------------------------------------------------------------------------
__global__ __launch_bounds__(256) void event_kernel(
    const float* __restrict__ x,        // (N,2)
    const float* __restrict__ t,        // (N,)
    const float* __restrict__ past_x,   // (N,M,2)
    const float* __restrict__ past_t,   // (N,M)
    const float* __restrict__ cov,      // (N,D)
    const float* __restrict__ x_grid,   // (G,2)
    const float* __restrict__ t_grid,   // (T,)
    const float* __restrict__ beta,     // (D,)
    const float* __restrict__ alpha_p,
    const float* __restrict__ sigma_p,
    const float* __restrict__ omega_p,
    float* __restrict__ out) {
    const int i   = blockIdx.x;
    const int tid = threadIdx.x;

    const float alpha = alpha_p[0];
    const float sigma = sigma_p[0];
    const float omega = omega_p[0];
    const float inv2s2 = 1.0f / (2.0f * sigma * sigma);
    const float c = alpha * omega / (6.283185307179586f * sigma * sigma);

    const float xi0 = x[2 * i];
    const float xi1 = x[2 * i + 1];
    const float ti  = t[i];

    // ---- past-event excitation: M=2048, 4 entries/thread/iter, 2 iters ----
    float excAcc = 0.0f;
    const float4* pt4 = (const float4*)(past_t + (size_t)i * M_PAST);
    const float4* px4 = (const float4*)(past_x + (size_t)i * M_PAST * 2);
    #pragma unroll
    for (int it = 0; it < M_PAST / 1024; ++it) {
        int j4 = it * 256 + tid;           // float4 index
        float4 pt = pt4[j4];
        float4 pa = px4[2 * j4];
        float4 pb = px4[2 * j4 + 1];
        {
            float dt_ = ti - pt.x;
            if (dt_ > 0.0f) {
                float d0 = xi0 - pa.x, d1 = xi1 - pa.y;
                excAcc += __expf(-(d0*d0 + d1*d1) * inv2s2 - omega * dt_);
            }
        }
        {
            float dt_ = ti - pt.y;
            if (dt_ > 0.0f) {
                float d0 = xi0 - pa.z, d1 = xi1 - pa.w;
                excAcc += __expf(-(d0*d0 + d1*d1) * inv2s2 - omega * dt_);
            }
        }
        {
            float dt_ = ti - pt.z;
            if (dt_ > 0.0f) {
                float d0 = xi0 - pb.x, d1 = xi1 - pb.y;
                excAcc += __expf(-(d0*d0 + d1*d1) * inv2s2 - omega * dt_);
            }
        }
        {
            float dt_ = ti - pt.w;
            if (dt_ > 0.0f) {
                float d0 = xi0 - pb.z, d1 = xi1 - pb.w;
                excAcc += __expf(-(d0*d0 + d1*d1) * inv2s2 - omega * dt_);
            }
        }
    }

    // ---- spatial grid sum: G=512, 2 per thread via one float4 ----
    float sgAcc = 0.0f;
    {
        const float4* xg4 = (const float4*)x_grid;
        float4 g = xg4[tid];
        float d0 = xi0 - g.x, d1 = xi1 - g.y;
        sgAcc += __expf(-(d0*d0 + d1*d1) * inv2s2);
        d0 = xi0 - g.z; d1 = xi1 - g.w;
        sgAcc += __expf(-(d0*d0 + d1*d1) * inv2s2);
    }

    // ---- temporal grid sum: T=64, threads 0..63 ----
    float ttAcc = 0.0f;
    if (tid < T_GRID) {
        float d = t_grid[tid] - ti;
        if (d > 0.0f) ttAcc = __expf(-omega * d);
    }

    // ---- block reductions (3 values) ----
    float a1 = excAcc, a2 = sgAcc, a3 = ttAcc;
    for (int o = 32; o > 0; o >>= 1) {
        a1 += __shfl_down(a1, o, 64);
        a2 += __shfl_down(a2, o, 64);
        a3 += __shfl_down(a3, o, 64);
    }
    __shared__ float s1[4], s2[4], s3[4];
    const int lane = tid & 63, wave = tid >> 6;
    if (lane == 0) { s1[wave] = a1; s2[wave] = a2; s3[wave] = a3; }
    __syncthreads();

    if (tid == 0) {
        float exc = s1[0] + s1[1] + s1[2] + s1[3];
        float sg  = s2[0] + s2[1] + s2[2] + s2[3];
        float tt  = s3[0] + s3[1] + s3[2] + s3[3];

        // baseline mu = max(cov_i . beta, EPS)
        float mu = 0.0f;
        const float* cv = cov + (size_t)i * D_COV;
        #pragma unroll
        for (int k = 0; k < D_COV; ++k) mu += cv[k] * beta[k];
        mu = fmaxf(mu, EPS_F);

        float lam = mu + c * exc;
        out[i] = __logf(lam + EPS_F);

        float dt_step = t_grid[1] - t_grid[0];
        float scale = (1.0f / (float)G_GRID) * dt_step;
        atomicAdd(out + N_EV, c * sg * tt * scale);
    }
}

extern "C" void kernel_launch(void* const* d_in, const int* in_sizes, int n_in,
                              void* d_out, int out_size, void* d_ws, size_t ws_size,
                              hipStream_t stream) {
    const float* x       = (const float*)d_in[0];
    const float* t       = (const float*)d_in[1];
    const float* past_x  = (const float*)d_in[2];
    const float* past_t  = (const float*)d_in[3];
    const float* cov     = (const float*)d_in[4];
    const float* z_grid  = (const float*)d_in[5];
    const float* x_grid  = (const float*)d_in[6];
    const float* t_grid  = (const float*)d_in[7];
    const float* beta    = (const float*)d_in[8];
    const float* alpha_p = (const float*)d_in[9];
    const float* sigma_p = (const float*)d_in[10];
    const float* omega_p = (const float*)d_in[11];
    float* out = (float*)d_out;

    zero_kernel<<<1, 1, 0, stream>>>(out);
    base_kernel<<<(T_GRID * G_GRID) / 256, 256, 0, stream>>>(z_grid, beta, t_grid, out);
    event_kernel<<<N_EV, 256, 0, stream>>>(x, t, past_x, past_t, cov,
                                           x_grid, t_grid, beta,
                                           alpha_p, sigma_p, omega_p, out);
}

// Round 2
// 96.050 us; speedup vs baseline: 1.1652x; 1.1652x over previous
//
#include <hip/hip_runtime.h>
#include <math.h>

#define N_EV   1024
#define M_PAST 2048
#define T_GRID 64
#define G_GRID 512
#define D_COV  16
#define EPS_F  1e-6f
#define ROWS_PER_BLOCK 32   // 32768 base-grid rows / 1024 blocks

// ---------------------------------------------------------------------------
// Kernel 1: one block (256 threads) per event i. Computes:
//   exc_i  = sum_j [t_i > past_t_ij] exp(-|x_i-past_x_ij|^2/(2s^2) - w*dt)
//   Sg_i   = sum_g exp(-|x_grid_g - x_i|^2/(2s^2))
//   Tt_i   = sum_ti [t_grid_ti > t_i] exp(-w*(t_grid_ti - t_i))
//   base_i = sum over 32 assigned z-grid rows of max(z.beta, EPS)
// Writes out[i] = log(max(cov_i.beta,EPS) + c*exc_i + EPS)
// and ws[i]     = base_i + c*Sg_i*Tt_i      (unscaled integral partial)
// ---------------------------------------------------------------------------
__global__ __launch_bounds__(256) void event_kernel(
    const float* __restrict__ x,        // (N,2)
    const float* __restrict__ t,        // (N,)
    const float* __restrict__ past_x,   // (N,M,2)
    const float* __restrict__ past_t,   // (N,M)
    const float* __restrict__ cov,      // (N,D)
    const float* __restrict__ z_grid,   // (T*G, D)
    const float* __restrict__ x_grid,   // (G,2)
    const float* __restrict__ t_grid,   // (T,)
    const float* __restrict__ beta,     // (D,)
    const float* __restrict__ alpha_p,
    const float* __restrict__ sigma_p,
    const float* __restrict__ omega_p,
    float* __restrict__ out,
    float* __restrict__ ws) {
    const int i   = blockIdx.x;
    const int tid = threadIdx.x;

    const float alpha = alpha_p[0];
    const float sigma = sigma_p[0];
    const float omega = omega_p[0];
    const float inv2s2 = 1.0f / (2.0f * sigma * sigma);
    const float c = alpha * omega / (6.283185307179586f * sigma * sigma);

    const float xi0 = x[2 * i];
    const float xi1 = x[2 * i + 1];
    const float ti  = t[i];

    // beta in registers (used by base rows and by the mu dot at tid==0)
    const float4* b4 = (const float4*)beta;
    const float4 b0 = b4[0], b1 = b4[1], b2 = b4[2], b3 = b4[3];

    // ---- past-event excitation: M=2048, 8 entries/thread ----
    float excAcc = 0.0f;
    const float4* pt4 = (const float4*)(past_t + (size_t)i * M_PAST);
    const float4* px4 = (const float4*)(past_x + (size_t)i * M_PAST * 2);
    #pragma unroll
    for (int it = 0; it < M_PAST / 1024; ++it) {
        int j4 = it * 256 + tid;
        float4 pt = pt4[j4];
        float4 pa = px4[2 * j4];
        float4 pb = px4[2 * j4 + 1];
        {
            float dt_ = ti - pt.x;
            float d0 = xi0 - pa.x, d1 = xi1 - pa.y;
            float e = __expf(-(d0*d0 + d1*d1) * inv2s2 - omega * dt_);
            excAcc += (dt_ > 0.0f) ? e : 0.0f;
        }
        {
            float dt_ = ti - pt.y;
            float d0 = xi0 - pa.z, d1 = xi1 - pa.w;
            float e = __expf(-(d0*d0 + d1*d1) * inv2s2 - omega * dt_);
            excAcc += (dt_ > 0.0f) ? e : 0.0f;
        }
        {
            float dt_ = ti - pt.z;
            float d0 = xi0 - pb.x, d1 = xi1 - pb.y;
            float e = __expf(-(d0*d0 + d1*d1) * inv2s2 - omega * dt_);
            excAcc += (dt_ > 0.0f) ? e : 0.0f;
        }
        {
            float dt_ = ti - pt.w;
            float d0 = xi0 - pb.z, d1 = xi1 - pb.w;
            float e = __expf(-(d0*d0 + d1*d1) * inv2s2 - omega * dt_);
            excAcc += (dt_ > 0.0f) ? e : 0.0f;
        }
    }

    // ---- spatial grid sum: G=512, 2 points/thread via one float4 ----
    float sgAcc = 0.0f;
    {
        const float4* xg4 = (const float4*)x_grid;
        float4 g = xg4[tid];
        float d0 = xi0 - g.x, d1 = xi1 - g.y;
        sgAcc  = __expf(-(d0*d0 + d1*d1) * inv2s2);
        d0 = xi0 - g.z; d1 = xi1 - g.w;
        sgAcc += __expf(-(d0*d0 + d1*d1) * inv2s2);
    }

    // ---- temporal grid sum: T=64 on threads 0..63 ----
    float ttAcc = 0.0f;
    if (tid < T_GRID) {
        float d = t_grid[tid] - ti;
        if (d > 0.0f) ttAcc = __expf(-omega * d);
    }

    // ---- base-intensity rows: 32 rows/block on threads 0..31 ----
    float baseAcc = 0.0f;
    if (tid < ROWS_PER_BLOCK) {
        int row = i * ROWS_PER_BLOCK + tid;
        const float4* z4 = (const float4*)(z_grid + (size_t)row * D_COV);
        float4 z0 = z4[0], z1 = z4[1], z2 = z4[2], z3 = z4[3];
        float dot = z0.x*b0.x + z0.y*b0.y + z0.z*b0.z + z0.w*b0.w
                  + z1.x*b1.x + z1.y*b1.y + z1.z*b1.z + z1.w*b1.w
                  + z2.x*b2.x + z2.y*b2.y + z2.z*b2.z + z2.w*b2.w
                  + z3.x*b3.x + z3.y*b3.y + z3.z*b3.z + z3.w*b3.w;
        baseAcc = fmaxf(dot, EPS_F);
    }

    // ---- block reductions (4 values) ----
    float a1 = excAcc, a2 = sgAcc, a3 = ttAcc, a4 = baseAcc;
    for (int o = 32; o > 0; o >>= 1) {
        a1 += __shfl_down(a1, o, 64);
        a2 += __shfl_down(a2, o, 64);
        a3 += __shfl_down(a3, o, 64);
        a4 += __shfl_down(a4, o, 64);
    }
    __shared__ float s1[4], s2[4], s3[4], s4[4];
    const int lane = tid & 63, wave = tid >> 6;
    if (lane == 0) { s1[wave] = a1; s2[wave] = a2; s3[wave] = a3; s4[wave] = a4; }
    __syncthreads();

    if (tid == 0) {
        float exc  = s1[0] + s1[1] + s1[2] + s1[3];
        float sg   = s2[0] + s2[1] + s2[2] + s2[3];
        float tt   = s3[0] + s3[1] + s3[2] + s3[3];
        float base = s4[0] + s4[1] + s4[2] + s4[3];

        // baseline mu = max(cov_i . beta, EPS), vectorized
        const float4* cv4 = (const float4*)(cov + (size_t)i * D_COV);
        float4 c0 = cv4[0], c1 = cv4[1], c2 = cv4[2], c3 = cv4[3];
        float mu = c0.x*b0.x + c0.y*b0.y + c0.z*b0.z + c0.w*b0.w
                 + c1.x*b1.x + c1.y*b1.y + c1.z*b1.z + c1.w*b1.w
                 + c2.x*b2.x + c2.y*b2.y + c2.z*b2.z + c2.w*b2.w
                 + c3.x*b3.x + c3.y*b3.y + c3.z*b3.z + c3.w*b3.w;
        mu = fmaxf(mu, EPS_F);

        out[i] = __logf(mu + c * exc + EPS_F);
        ws[i]  = base + c * sg * tt;    // unscaled integral partial
    }
}

// ---------------------------------------------------------------------------
// Kernel 2: reduce 1024 partials -> out[N] with the dxdy*dt scaling.
// One block of 1024 threads (16 waves).
// ---------------------------------------------------------------------------
__global__ __launch_bounds__(1024) void reduce_kernel(
    const float* __restrict__ ws,
    const float* __restrict__ t_grid,
    float* __restrict__ out) {
    const int tid = threadIdx.x;
    float v = ws[tid];
    for (int o = 32; o > 0; o >>= 1) v += __shfl_down(v, o, 64);
    __shared__ float sw[16];
    const int lane = tid & 63, wave = tid >> 6;
    if (lane == 0) sw[wave] = v;
    __syncthreads();
    if (tid == 0) {
        float s = 0.0f;
        #pragma unroll
        for (int w = 0; w < 16; ++w) s += sw[w];
        float dt_step = t_grid[1] - t_grid[0];
        out[N_EV] = s * (1.0f / (float)G_GRID) * dt_step;
    }
}

extern "C" void kernel_launch(void* const* d_in, const int* in_sizes, int n_in,
                              void* d_out, int out_size, void* d_ws, size_t ws_size,
                              hipStream_t stream) {
    const float* x       = (const float*)d_in[0];
    const float* t       = (const float*)d_in[1];
    const float* past_x  = (const float*)d_in[2];
    const float* past_t  = (const float*)d_in[3];
    const float* cov     = (const float*)d_in[4];
    const float* z_grid  = (const float*)d_in[5];
    const float* x_grid  = (const float*)d_in[6];
    const float* t_grid  = (const float*)d_in[7];
    const float* beta    = (const float*)d_in[8];
    const float* alpha_p = (const float*)d_in[9];
    const float* sigma_p = (const float*)d_in[10];
    const float* omega_p = (const float*)d_in[11];
    float* out = (float*)d_out;
    float* ws  = (float*)d_ws;

    event_kernel<<<N_EV, 256, 0, stream>>>(x, t, past_x, past_t, cov, z_grid,
                                           x_grid, t_grid, beta,
                                           alpha_p, sigma_p, omega_p, out, ws);
    reduce_kernel<<<1, 1024, 0, stream>>>(ws, t_grid, out);
}